// Round 1
// baseline (2270.088 us; speedup 1.0000x reference)
//
#include <hip/hip_runtime.h>
#include <math.h>

#define N_ATOMS 50000
#define M_NBR   12
#define A_FEA   64
#define B_FEA   41
#define KF      169      // 2*A + B
#define OC      128      // 2*A
#define NROW    600000   // N_ATOMS * M_NBR
#define TILE_R  64
#define BN_EPS  1e-5f

// d_ws float layout
#define WS_SUM1   0
#define WS_SUMSQ1 128
#define WS_SUM2   256
#define WS_SUMSQ2 320
#define WS_NFLOAT 384

__device__ __forceinline__ float softplusf(float x) {
    // stable: max(x,0) + log1p(exp(-|x|))
    return fmaxf(x, 0.f) + log1pf(expf(-fabsf(x)));
}
__device__ __forceinline__ float sigmoidf(float x) {
    return 1.f / (1.f + expf(-x));
}

// Zero d_out (used as nbr_sumed accumulator) and the stats scratch.
__global__ void k_zero(float* __restrict__ dout, float* __restrict__ stats) {
    int i = blockIdx.x * blockDim.x + threadIdx.x;
    int stride = gridDim.x * blockDim.x;
    for (int j = i; j < N_ATOMS * A_FEA; j += stride) dout[j] = 0.f;
    if (i < WS_NFLOAT) stats[i] = 0.f;
}

// Stage W transposed into LDS: Wt[k][c] (k-major). LDS writes are contiguous
// (conflict-free); global reads are strided but L2-served, once per block.
__device__ __forceinline__ void stage_W(float* __restrict__ Wt,
                                        const float* __restrict__ W, int tid) {
    for (int i = tid; i < KF * OC; i += 256) {
        int k = i >> 7;        // OC = 128
        int c = i & 127;
        Wt[i] = W[c * KF + k]; // Wt[k*128 + c]
    }
}

// Stage a 64-row A-tile: At[k][r] = feature k of row rb+r.
// i enumerated k-major -> LDS writes contiguous (conflict-free); each wave
// handles one k for r=0..63 (uniform branch).
__device__ __forceinline__ void stage_tile(float* __restrict__ At,
                                           const float* __restrict__ atom,
                                           const float* __restrict__ nbr,
                                           const int* __restrict__ idx,
                                           int rb, int tid) {
    for (int i = tid; i < KF * TILE_R; i += 256) {
        int k = i >> 6;        // TILE_R = 64
        int r = i & 63;
        int row = rb + r;
        float v;
        if (k < A_FEA) {
            v = atom[(row / M_NBR) * A_FEA + k];
        } else if (k < 2 * A_FEA) {
            v = atom[idx[row] * A_FEA + (k - A_FEA)];
        } else {
            v = nbr[row * B_FEA + (k - 2 * A_FEA)];
        }
        At[i] = v;             // At[k*64 + r]
    }
}

// Register-tiled fp32 GEMM core: thread (tr,tc) computes rows rb+4tr..+3,
// channels 4tc..4tc+3 (accA, filter half) and 64+4tc..+3 (accB, core half).
// All LDS reads are aligned float4; A-read broadcasts, W-reads are
// lane-contiguous (2-way bank aliasing, free).
__device__ __forceinline__ void gemm_tile(const float* __restrict__ At,
                                          const float* __restrict__ Wt,
                                          int tr, int tc,
                                          float accA[4][4], float accB[4][4]) {
#pragma unroll 4
    for (int k = 0; k < KF; ++k) {
        const float4 av  = *(const float4*)(At + k * TILE_R + (tr << 2));
        const float4 wav = *(const float4*)(Wt + k * OC + (tc << 2));
        const float4 wbv = *(const float4*)(Wt + k * OC + 64 + (tc << 2));
        const float a[4]  = {av.x, av.y, av.z, av.w};
        const float wa[4] = {wav.x, wav.y, wav.z, wav.w};
        const float wb[4] = {wbv.x, wbv.y, wbv.z, wbv.w};
#pragma unroll
        for (int i = 0; i < 4; ++i) {
#pragma unroll
            for (int j = 0; j < 4; ++j) {
                accA[i][j] = fmaf(a[i], wa[j], accA[i][j]);
                accB[i][j] = fmaf(a[i], wb[j], accB[i][j]);
            }
        }
    }
}

// Pass 1: GEMM, accumulate per-channel sum / sumsq of (acc + bias) for BN1.
__global__ __launch_bounds__(256, 1)
void k_gemm_stats(const float* __restrict__ atom, const float* __restrict__ nbr,
                  const int* __restrict__ idx, const float* __restrict__ W,
                  const float* __restrict__ bias, float* __restrict__ stats) {
    __shared__ __align__(16) float Wt[KF * OC];      // 86528 B
    __shared__ __align__(16) float At[KF * TILE_R];  // 43264 B
    int tid = threadIdx.x;
    stage_W(Wt, W, tid);
    int tc = tid & 15, tr = tid >> 4;

    float bA[4], bB[4];
#pragma unroll
    for (int j = 0; j < 4; ++j) {
        bA[j] = bias[(tc << 2) + j];
        bB[j] = bias[64 + (tc << 2) + j];
    }
    float sA[4] = {0}, qA[4] = {0}, sB[4] = {0}, qB[4] = {0};

    for (int rb = blockIdx.x * TILE_R; rb < NROW; rb += gridDim.x * TILE_R) {
        __syncthreads();   // previous tile's At reads complete
        stage_tile(At, atom, nbr, idx, rb, tid);
        __syncthreads();   // At (and first-iter Wt) visible
        float accA[4][4] = {{0}}, accB[4][4] = {{0}};
        gemm_tile(At, Wt, tr, tc, accA, accB);
#pragma unroll
        for (int i = 0; i < 4; ++i) {
#pragma unroll
            for (int j = 0; j < 4; ++j) {
                float gA = accA[i][j] + bA[j];
                float gB = accB[i][j] + bB[j];
                sA[j] += gA; qA[j] = fmaf(gA, gA, qA[j]);
                sB[j] += gB; qB[j] = fmaf(gB, gB, qB[j]);
            }
        }
    }
#pragma unroll
    for (int j = 0; j < 4; ++j) {
        int cA = (tc << 2) + j, cB = 64 + (tc << 2) + j;
        atomicAdd(&stats[WS_SUM1 + cA], sA[j]);
        atomicAdd(&stats[WS_SUMSQ1 + cA], qA[j]);
        atomicAdd(&stats[WS_SUM1 + cB], sB[j]);
        atomicAdd(&stats[WS_SUMSQ1 + cB], qB[j]);
    }
}

// Pass 2: GEMM again, apply BN1, sigmoid(filter)*softplus(core), sum over m
// (LDS partials per local atom, flushed with global atomics into zeroed d_out).
__global__ __launch_bounds__(256, 1)
void k_gemm_main(const float* __restrict__ atom, const float* __restrict__ nbr,
                 const int* __restrict__ idx, const float* __restrict__ W,
                 const float* __restrict__ bias,
                 const float* __restrict__ g1, const float* __restrict__ b1,
                 const float* __restrict__ stats, float* __restrict__ dout) {
    __shared__ __align__(16) float Wt[KF * OC];
    __shared__ __align__(16) float At[KF * TILE_R];
    __shared__ float S[7 * 64];   // per-tile atom partial sums (<=7 atoms/tile)
    int tid = threadIdx.x;
    stage_W(Wt, W, tid);
    for (int i = tid; i < 7 * 64; i += 256) S[i] = 0.f;
    int tc = tid & 15, tr = tid >> 4;

    // Per-thread BN1 affine for its 8 channels (bias folded in).
    const float invn = 1.f / (float)NROW;
    float scA[4], shA[4], scB[4], shB[4];
#pragma unroll
    for (int j = 0; j < 4; ++j) {
        {
            int c = (tc << 2) + j;
            float mean = stats[WS_SUM1 + c] * invn;
            float var  = stats[WS_SUMSQ1 + c] * invn - mean * mean;
            float sc   = g1[c] * rsqrtf(var + BN_EPS);
            scA[j] = sc; shA[j] = b1[c] + (bias[c] - mean) * sc;
        }
        {
            int c = 64 + (tc << 2) + j;
            float mean = stats[WS_SUM1 + c] * invn;
            float var  = stats[WS_SUMSQ1 + c] * invn - mean * mean;
            float sc   = g1[c] * rsqrtf(var + BN_EPS);
            scB[j] = sc; shB[j] = b1[c] + (bias[c] - mean) * sc;
        }
    }

    for (int rb = blockIdx.x * TILE_R; rb < NROW; rb += gridDim.x * TILE_R) {
        __syncthreads();   // prior At reads done; S zeroing visible
        stage_tile(At, atom, nbr, idx, rb, tid);
        __syncthreads();
        float accA[4][4] = {{0}}, accB[4][4] = {{0}};
        gemm_tile(At, Wt, tr, tc, accA, accB);

        int a0 = rb / M_NBR;
#pragma unroll
        for (int i = 0; i < 4; ++i) {
            int row = rb + (tr << 2) + i;
            int al = row / M_NBR - a0;     // 0..6
#pragma unroll
            for (int j = 0; j < 4; ++j) {
                float gA = fmaf(accA[i][j], scA[j], shA[j]);
                float gB = fmaf(accB[i][j], scB[j], shB[j]);
                float t = sigmoidf(gA) * softplusf(gB);
                atomicAdd(&S[al * 64 + (tc << 2) + j], t);
            }
        }
        __syncthreads();   // S complete, At reads done
        int amax = (rb + TILE_R - 1) / M_NBR - a0;
        for (int i = tid; i < 7 * 64; i += 256) {
            float v = S[i];
            S[i] = 0.f;    // same thread reads & zeroes -> no hazard
            int a = i >> 6;
            if (a <= amax) atomicAdd(&dout[(a0 + a) * 64 + (i & 63)], v);
        }
        // next loop-top __syncthreads() orders zeroed S before reuse
    }
}

// BN2 stats over d_out (N_ATOMS x 64).
__global__ __launch_bounds__(256, 1)
void k_bn2_stats(const float* __restrict__ dout, float* __restrict__ stats) {
    int tid = threadIdx.x;
    int c = tid & 63;
    int g = tid >> 6;   // 0..3
    float s = 0.f, q = 0.f;
    for (int n = blockIdx.x * 4 + g; n < N_ATOMS; n += gridDim.x * 4) {
        float v = dout[n * 64 + c];
        s += v; q = fmaf(v, v, q);
    }
    __shared__ float red[4][64];
    red[g][c] = s;
    __syncthreads();
    if (g == 0)
        atomicAdd(&stats[WS_SUM2 + c], red[0][c] + red[1][c] + red[2][c] + red[3][c]);
    __syncthreads();
    red[g][c] = q;
    __syncthreads();
    if (g == 0)
        atomicAdd(&stats[WS_SUMSQ2 + c], red[0][c] + red[1][c] + red[2][c] + red[3][c]);
}

// Final: out = softplus(atom + BN2(nbr_sumed)), in place on d_out.
__global__ void k_final(const float* __restrict__ atom, const float* __restrict__ g2,
                        const float* __restrict__ b2, const float* __restrict__ stats,
                        float* __restrict__ dout) {
    int i0 = blockIdx.x * blockDim.x + threadIdx.x;
    int c = i0 & 63;                       // stride is a multiple of 64
    const float invn = 1.f / (float)N_ATOMS;
    float mean = stats[WS_SUM2 + c] * invn;
    float var  = stats[WS_SUMSQ2 + c] * invn - mean * mean;
    float sc   = g2[c] * rsqrtf(var + BN_EPS);
    float sh   = b2[c] - mean * sc;
    int stride = gridDim.x * blockDim.x;
    for (int i = i0; i < N_ATOMS * A_FEA; i += stride) {
        float v = fmaf(dout[i], sc, sh) + atom[i];
        dout[i] = softplusf(v);
    }
}

extern "C" void kernel_launch(void* const* d_in, const int* in_sizes, int n_in,
                              void* d_out, int out_size, void* d_ws, size_t ws_size,
                              hipStream_t stream) {
    const float* atom = (const float*)d_in[0];
    const float* nbr  = (const float*)d_in[1];
    const int*   idx  = (const int*)d_in[2];
    const float* W    = (const float*)d_in[3];
    const float* bias = (const float*)d_in[4];
    const float* g1   = (const float*)d_in[5];
    const float* b1   = (const float*)d_in[6];
    const float* g2   = (const float*)d_in[7];
    const float* b2   = (const float*)d_in[8];
    float* dout  = (float*)d_out;
    float* stats = (float*)d_ws;

    k_zero<<<512, 256, 0, stream>>>(dout, stats);
    k_gemm_stats<<<256, 256, 0, stream>>>(atom, nbr, idx, W, bias, stats);
    k_gemm_main<<<256, 256, 0, stream>>>(atom, nbr, idx, W, bias, g1, b1, stats, dout);
    k_bn2_stats<<<256, 256, 0, stream>>>(dout, stats);
    k_final<<<512, 256, 0, stream>>>(atom, g2, b2, stats, dout);
}

// Round 2
// 748.080 us; speedup vs baseline: 3.0346x; 3.0346x over previous
//
#include <hip/hip_runtime.h>
#include <math.h>

#define N_ATOMS 50000
#define M_NBR   12
#define A_FEA   64
#define B_FEA   41
#define KF      169      // 2*A + B
#define KP      192      // padded K (6 chunks of 32)
#define LDA     200      // LDS row stride in bf16 elems (400 B = free 2-way banking)
#define OC      128      // 2*A
#define NROW    600000   // N_ATOMS * M_NBR
#define TILE_R  64
#define BN_EPS  1e-5f

// d_ws float layout
#define WS_SUM1   0
#define WS_SUMSQ1 128
#define WS_SUM2   256
#define WS_SUMSQ2 320
#define WS_NFLOAT 384

typedef __attribute__((ext_vector_type(8))) short s16x8;
typedef __attribute__((ext_vector_type(4))) float f32x4;

__device__ __forceinline__ float softplusf(float x) {
    return fmaxf(x, 0.f) + log1pf(expf(-fabsf(x)));
}
__device__ __forceinline__ float sigmoidf(float x) {
    return 1.f / (1.f + expf(-x));
}
__device__ __forceinline__ unsigned short f2bf(float f) {
    unsigned int u = __float_as_uint(f);
    u += 0x7FFFu + ((u >> 16) & 1u);     // round-to-nearest-even
    return (unsigned short)(u >> 16);
}
__device__ __forceinline__ unsigned int pack2bf(float lo, float hi) {
    return (unsigned int)f2bf(lo) | ((unsigned int)f2bf(hi) << 16);
}

__global__ void k_zero(float* __restrict__ dout, float* __restrict__ stats) {
    int i = blockIdx.x * blockDim.x + threadIdx.x;
    int stride = gridDim.x * blockDim.x;
    for (int j = i; j < N_ATOMS * A_FEA; j += stride) dout[j] = 0.f;
    if (i < WS_NFLOAT) stats[i] = 0.f;
}

// ---- shared staging helpers -------------------------------------------------

// One-time: W (fp32, [c][k], k<169) -> LDS bf16 Wb[c][LDA], zero-padded k>=169.
__device__ __forceinline__ void stage_W(unsigned short* __restrict__ Wb,
                                        const float* __restrict__ W, int tid) {
    for (unsigned i = tid; i < OC * KP; i += 256) {
        unsigned c = i / (unsigned)KP;
        unsigned k = i - c * KP;
        float v = (k < KF) ? W[c * KF + k] : 0.f;
        Wb[c * LDA + k] = f2bf(v);
    }
}

// One-time: zero A-tile K-pad region [169, 192) for all 64 rows.
__device__ __forceinline__ void zero_At_pad(unsigned short* __restrict__ At, int tid) {
    for (unsigned i = tid; i < TILE_R * (KP - KF); i += 256) {
        unsigned r = i / (unsigned)(KP - KF);
        unsigned j = KF + (i - r * (KP - KF));
        At[r * LDA + j] = 0;
    }
}

// Per-tile: build 64 x 169 bf16 rows: [self(64) | nbr_atom(64) | nbr_fea(41)].
__device__ __forceinline__ void stage_tile(unsigned short* __restrict__ At,
                                           const float* __restrict__ atom,
                                           const float* __restrict__ nbr,
                                           const int* __restrict__ idx,
                                           int rb, int tid) {
    // phase 1: self features, float2 -> packed u32 LDS writes (conflict-free)
#pragma unroll
    for (unsigned i = tid; i < TILE_R * 32; i += 256) {
        unsigned r = i >> 5, k = (i & 31) * 2;
        unsigned a = (unsigned)(rb + r) / 12u;
        const float2 v = *(const float2*)(atom + a * A_FEA + k);
        *(unsigned int*)&At[r * LDA + k] = pack2bf(v.x, v.y);
    }
    // phase 2: gathered neighbor atom features
#pragma unroll
    for (unsigned i = tid; i < TILE_R * 32; i += 256) {
        unsigned r = i >> 5, k = (i & 31) * 2;
        int nb = idx[rb + r];
        const float2 v = *(const float2*)(atom + nb * A_FEA + k);
        *(unsigned int*)&At[r * LDA + A_FEA + k] = pack2bf(v.x, v.y);
    }
    // phase 3: bond features (41 per row, scalar; global reads fully consecutive)
#pragma unroll
    for (unsigned i = tid; i < TILE_R * B_FEA; i += 256) {
        unsigned r = i / (unsigned)B_FEA;
        unsigned j = i - r * B_FEA;
        float v = nbr[(unsigned)(rb + r) * B_FEA + j];
        At[r * LDA + 2 * A_FEA + j] = f2bf(v);
    }
}

// ---- pass 1: MFMA GEMM, accumulate per-channel sum/sumsq of acc (bias cancels in BN)
__global__ __launch_bounds__(256, 2)
void k_gemm_stats(const float* __restrict__ atom, const float* __restrict__ nbr,
                  const int* __restrict__ idx, const float* __restrict__ W,
                  float* __restrict__ stats) {
    __shared__ __align__(16) unsigned short Wb[OC * LDA];      // 51200 B
    __shared__ __align__(16) unsigned short At[TILE_R * LDA];  // 25600 B
    const int tid = threadIdx.x;
    stage_W(Wb, W, tid);
    zero_At_pad(At, tid);

    const int lane = tid & 63;
    const int w    = tid >> 6;
    const int col  = lane & 15;
    const int q8   = (lane >> 4) * 8;
    const int r0   = (w & 1) * 32;
    const int g    = w >> 1;
    const int ct[4] = {2 * g, 2 * g + 1, 2 * g + 4, 2 * g + 5};

    float s[4] = {0.f, 0.f, 0.f, 0.f}, q[4] = {0.f, 0.f, 0.f, 0.f};

    for (int rb = blockIdx.x * TILE_R; rb < NROW; rb += gridDim.x * TILE_R) {
        __syncthreads();                 // prior tile's LDS reads complete
        stage_tile(At, atom, nbr, idx, rb, tid);
        __syncthreads();                 // At (and first-iter Wb/pad) visible

        f32x4 acc[2][4];
#pragma unroll
        for (int rt = 0; rt < 2; ++rt)
#pragma unroll
            for (int t = 0; t < 4; ++t) acc[rt][t] = (f32x4){0.f, 0.f, 0.f, 0.f};

#pragma unroll
        for (int kc = 0; kc < 6; ++kc) {
            const int k0 = kc * 32;
            const s16x8 a0 = *(const s16x8*)&At[(r0 + col) * LDA + k0 + q8];
            const s16x8 a1 = *(const s16x8*)&At[(r0 + 16 + col) * LDA + k0 + q8];
#pragma unroll
            for (int t = 0; t < 4; ++t) {
                const s16x8 b = *(const s16x8*)&Wb[(ct[t] * 16 + col) * LDA + k0 + q8];
                acc[0][t] = __builtin_amdgcn_mfma_f32_16x16x32_bf16(a0, b, acc[0][t], 0, 0, 0);
                acc[1][t] = __builtin_amdgcn_mfma_f32_16x16x32_bf16(a1, b, acc[1][t], 0, 0, 0);
            }
        }
#pragma unroll
        for (int t = 0; t < 4; ++t)
#pragma unroll
            for (int rt = 0; rt < 2; ++rt)
#pragma unroll
                for (int e = 0; e < 4; ++e) {
                    float v = acc[rt][t][e];
                    s[t] += v; q[t] = fmaf(v, v, q[t]);
                }
    }
    // reduce across the 4 quads (same channel col), then one atomic per channel
#pragma unroll
    for (int t = 0; t < 4; ++t) {
        float sv = s[t], qv = q[t];
        sv += __shfl_xor(sv, 16); sv += __shfl_xor(sv, 32);
        qv += __shfl_xor(qv, 16); qv += __shfl_xor(qv, 32);
        if (lane < 16) {
            int c = ct[t] * 16 + col;
            atomicAdd(&stats[WS_SUM1 + c], sv);
            atomicAdd(&stats[WS_SUMSQ1 + c], qv);
        }
    }
}

// ---- pass 2: MFMA GEMM + BN1 + sigmoid*softplus + m-sum into d_out
__global__ __launch_bounds__(256, 2)
void k_gemm_main(const float* __restrict__ atom, const float* __restrict__ nbr,
                 const int* __restrict__ idx, const float* __restrict__ W,
                 const float* __restrict__ g1, const float* __restrict__ b1,
                 const float* __restrict__ stats, float* __restrict__ dout) {
    __shared__ __align__(16) unsigned short Wb[OC * LDA];
    __shared__ __align__(16) unsigned short At[TILE_R * LDA];
    __shared__ float S[7 * 64];
    const int tid = threadIdx.x;
    stage_W(Wb, W, tid);
    zero_At_pad(At, tid);
    for (int i = tid; i < 7 * 64; i += 256) S[i] = 0.f;

    const int lane = tid & 63;
    const int w    = tid >> 6;
    const int col  = lane & 15;
    const int q8   = (lane >> 4) * 8;
    const int r0   = (w & 1) * 32;
    const int g    = w >> 1;
    const int ct[4] = {2 * g, 2 * g + 1, 2 * g + 4, 2 * g + 5};

    // BN1 affine per lane-channel (bias b cancels against the mean)
    const float invn = 1.f / (float)NROW;
    float sc[4], sh[4];
#pragma unroll
    for (int t = 0; t < 4; ++t) {
        int c = ct[t] * 16 + col;
        float mean = stats[WS_SUM1 + c] * invn;
        float var  = stats[WS_SUMSQ1 + c] * invn - mean * mean;
        sc[t] = g1[c] * rsqrtf(var + BN_EPS);
        sh[t] = b1[c] - mean * sc[t];
    }

    for (int rb = blockIdx.x * TILE_R; rb < NROW; rb += gridDim.x * TILE_R) {
        __syncthreads();                 // prior LDS reads + S flush complete
        stage_tile(At, atom, nbr, idx, rb, tid);
        __syncthreads();

        f32x4 acc[2][4];
#pragma unroll
        for (int rt = 0; rt < 2; ++rt)
#pragma unroll
            for (int t = 0; t < 4; ++t) acc[rt][t] = (f32x4){0.f, 0.f, 0.f, 0.f};

#pragma unroll
        for (int kc = 0; kc < 6; ++kc) {
            const int k0 = kc * 32;
            const s16x8 a0 = *(const s16x8*)&At[(r0 + col) * LDA + k0 + q8];
            const s16x8 a1 = *(const s16x8*)&At[(r0 + 16 + col) * LDA + k0 + q8];
#pragma unroll
            for (int t = 0; t < 4; ++t) {
                const s16x8 b = *(const s16x8*)&Wb[(ct[t] * 16 + col) * LDA + k0 + q8];
                acc[0][t] = __builtin_amdgcn_mfma_f32_16x16x32_bf16(a0, b, acc[0][t], 0, 0, 0);
                acc[1][t] = __builtin_amdgcn_mfma_f32_16x16x32_bf16(a1, b, acc[1][t], 0, 0, 0);
            }
        }

        const int a0i = rb / M_NBR;
#pragma unroll
        for (int p = 0; p < 2; ++p) {            // (filter t=p, core t=p+2), same lane map
            const int c = ct[p] * 16 + col;      // filter channel in [0,64)
#pragma unroll
            for (int rt = 0; rt < 2; ++rt)
#pragma unroll
                for (int e = 0; e < 4; ++e) {
                    float gF = fmaf(acc[rt][p][e],     sc[p],     sh[p]);
                    float gC = fmaf(acc[rt][p + 2][e], sc[p + 2], sh[p + 2]);
                    float v  = sigmoidf(gF) * softplusf(gC);
                    int row_local = r0 + rt * 16 + (lane >> 4) * 4 + e;
                    int al = (rb + row_local) / M_NBR - a0i;   // 0..6
                    atomicAdd(&S[al * 64 + c], v);
                }
        }
        __syncthreads();                 // S complete
        const int amax = (rb + TILE_R - 1) / M_NBR - a0i;
        for (int i = tid; i < 7 * 64; i += 256) {
            float v = S[i];
            S[i] = 0.f;                  // same thread reads & zeroes
            int a = i >> 6;
            if (a <= amax) atomicAdd(&dout[(a0i + a) * 64 + (i & 63)], v);
        }
    }
}

// BN2 stats over d_out (N_ATOMS x 64).
__global__ __launch_bounds__(256, 1)
void k_bn2_stats(const float* __restrict__ dout, float* __restrict__ stats) {
    int tid = threadIdx.x;
    int c = tid & 63;
    int g = tid >> 6;
    float s = 0.f, q = 0.f;
    for (int n = blockIdx.x * 4 + g; n < N_ATOMS; n += gridDim.x * 4) {
        float v = dout[n * 64 + c];
        s += v; q = fmaf(v, v, q);
    }
    __shared__ float red[4][64];
    red[g][c] = s;
    __syncthreads();
    if (g == 0)
        atomicAdd(&stats[WS_SUM2 + c], red[0][c] + red[1][c] + red[2][c] + red[3][c]);
    __syncthreads();
    red[g][c] = q;
    __syncthreads();
    if (g == 0)
        atomicAdd(&stats[WS_SUMSQ2 + c], red[0][c] + red[1][c] + red[2][c] + red[3][c]);
}

__global__ void k_final(const float* __restrict__ atom, const float* __restrict__ g2,
                        const float* __restrict__ b2, const float* __restrict__ stats,
                        float* __restrict__ dout) {
    int i0 = blockIdx.x * blockDim.x + threadIdx.x;
    int c = i0 & 63;
    const float invn = 1.f / (float)N_ATOMS;
    float mean = stats[WS_SUM2 + c] * invn;
    float var  = stats[WS_SUMSQ2 + c] * invn - mean * mean;
    float sc   = g2[c] * rsqrtf(var + BN_EPS);
    float sh   = b2[c] - mean * sc;
    int stride = gridDim.x * blockDim.x;
    for (int i = i0; i < N_ATOMS * A_FEA; i += stride) {
        float v = fmaf(dout[i], sc, sh) + atom[i];
        dout[i] = softplusf(v);
    }
}

extern "C" void kernel_launch(void* const* d_in, const int* in_sizes, int n_in,
                              void* d_out, int out_size, void* d_ws, size_t ws_size,
                              hipStream_t stream) {
    const float* atom = (const float*)d_in[0];
    const float* nbr  = (const float*)d_in[1];
    const int*   idx  = (const int*)d_in[2];
    const float* W    = (const float*)d_in[3];
    // d_in[4] (bias b) is mathematically absorbed by BN1 -> unused
    const float* g1   = (const float*)d_in[5];
    const float* b1   = (const float*)d_in[6];
    const float* g2   = (const float*)d_in[7];
    const float* b2   = (const float*)d_in[8];
    float* dout  = (float*)d_out;
    float* stats = (float*)d_ws;

    k_zero<<<512, 256, 0, stream>>>(dout, stats);
    k_gemm_stats<<<512, 256, 0, stream>>>(atom, nbr, idx, W, stats);
    k_gemm_main<<<512, 256, 0, stream>>>(atom, nbr, idx, W, g1, b1, stats, dout);
    k_bn2_stats<<<256, 256, 0, stream>>>(dout, stats);
    k_final<<<512, 256, 0, stream>>>(atom, g2, b2, stats, dout);
}

// Round 3
// 555.426 us; speedup vs baseline: 4.0871x; 1.3469x over previous
//
#include <hip/hip_runtime.h>
#include <math.h>

#define N_ATOMS 50000
#define M_NBR   12
#define A_FEA   64
#define B_FEA   41
#define KF      169      // 2*A + B
#define KP      192      // padded K (6 chunks of 32)
#define LDA     200      // LDS row stride in bf16 (400 B -> free 2-way banking)
#define OC      128      // 2*A
#define NROW    600000   // N_ATOMS * M_NBR
#define TILE_R  64
#define BN_EPS  1e-5f
#define L2E     1.44269504088896340736f
#define LN2     0.693147180559945309417f

// d_ws float layout
#define WS_SUM1   0
#define WS_SUMSQ1 128
#define WS_SUM2   256
#define WS_SUMSQ2 320
#define WS_NFLOAT 384

typedef __attribute__((ext_vector_type(8))) short s16x8;
typedef __attribute__((ext_vector_type(4))) float f32x4;

__device__ __forceinline__ float fsigmoid(float x) {
    float e = __builtin_amdgcn_exp2f(-x * L2E);
    return __builtin_amdgcn_rcpf(1.f + e);
}
__device__ __forceinline__ float fsoftplus(float x) {
    float e = __builtin_amdgcn_exp2f(-fabsf(x) * L2E);
    return fmaxf(x, 0.f) + __builtin_amdgcn_logf(1.f + e) * LN2;
}
__device__ __forceinline__ unsigned short f2bf(float f) {
    unsigned int u = __float_as_uint(f);
    u += 0x7FFFu + ((u >> 16) & 1u);     // RNE
    return (unsigned short)(u >> 16);
}
__device__ __forceinline__ unsigned int pack2bf(float lo, float hi) {
    return (unsigned int)f2bf(lo) | ((unsigned int)f2bf(hi) << 16);
}

__global__ void k_zero(float* __restrict__ dout, float* __restrict__ stats) {
    int i = blockIdx.x * blockDim.x + threadIdx.x;
    int stride = gridDim.x * blockDim.x;
    for (int j = i; j < N_ATOMS * A_FEA; j += stride) dout[j] = 0.f;
    if (i < WS_NFLOAT) stats[i] = 0.f;
}

// One-time: W (fp32, [c][k]) -> LDS bf16 Wb[c][LDA], zero-padded k>=169.
__device__ __forceinline__ void stage_W(unsigned short* __restrict__ Wb,
                                        const float* __restrict__ W, int tid) {
    for (unsigned i = tid; i < OC * KP; i += 256) {
        unsigned c = i / (unsigned)KP;
        unsigned k = i - c * KP;
        float v = (k < KF) ? W[c * KF + k] : 0.f;
        Wb[c * LDA + k] = f2bf(v);
    }
}

__device__ __forceinline__ void zero_At_pad(unsigned short* __restrict__ At, int tid) {
    for (unsigned i = tid; i < TILE_R * (KP - KF); i += 256) {
        unsigned r = i / (unsigned)(KP - KF);
        unsigned j = KF + (i - r * (KP - KF));
        At[r * LDA + j] = 0;
    }
}

// Latency-batched tile staging: ALL independent global loads issued first
// (compile-time trip counts -> fully unrolled, loads stay in flight), then the
// dependent gathers, then convert + LDS writes. ~2 exposed latencies per tile
// instead of ~16 serialized ones.
__device__ __forceinline__ void stage_tile(unsigned short* __restrict__ At,
                                           const float* __restrict__ atom,
                                           const float* __restrict__ nbr,
                                           const int* __restrict__ idx,
                                           int rb, int tid) {
    const int r8 = tid >> 5;          // rows r8 + 8*it
    const int k2 = (tid & 31) * 2;    // float2 k-offset
    float2 selfv[8];
    int    nbi[8];
    float  bondv[10];
#pragma unroll
    for (int it = 0; it < 8; ++it) {
        int row = rb + r8 + it * 8;
        selfv[it] = *(const float2*)(atom + ((unsigned)row / 12u) * A_FEA + k2);
    }
#pragma unroll
    for (int it = 0; it < 8; ++it) nbi[it] = idx[rb + r8 + it * 8];
#pragma unroll
    for (int it = 0; it < 10; ++it)   // rows [rb,rb+64) of nbr are contiguous
        bondv[it] = nbr[(size_t)rb * B_FEA + tid + it * 256];
    float tailv = 0.f;
    if (tid < TILE_R * B_FEA - 2560)  // 64 leftover elements
        tailv = nbr[(size_t)rb * B_FEA + 2560 + tid];
    float2 gat[8];
#pragma unroll
    for (int it = 0; it < 8; ++it)
        gat[it] = *(const float2*)(atom + (unsigned)nbi[it] * A_FEA + k2);
#pragma unroll
    for (int it = 0; it < 8; ++it) {
        int r = r8 + it * 8;
        *(unsigned int*)&At[r * LDA + k2]          = pack2bf(selfv[it].x, selfv[it].y);
        *(unsigned int*)&At[r * LDA + A_FEA + k2]  = pack2bf(gat[it].x, gat[it].y);
    }
#pragma unroll
    for (int it = 0; it < 10; ++it) {
        unsigned i = tid + it * 256;
        unsigned r = i / 41u, j = i - r * 41u;
        At[r * LDA + 2 * A_FEA + j] = f2bf(bondv[it]);
    }
    if (tid < TILE_R * B_FEA - 2560) {
        unsigned i = 2560 + tid;
        unsigned r = i / 41u, j = i - r * 41u;
        At[r * LDA + 2 * A_FEA + j] = f2bf(tailv);
    }
}

// ---- pass 1: MFMA GEMM, per-channel sum/sumsq (linear bias cancels in BN1)
__global__ __launch_bounds__(256, 2)
void k_gemm_stats(const float* __restrict__ atom, const float* __restrict__ nbr,
                  const int* __restrict__ idx, const float* __restrict__ W,
                  float* __restrict__ stats) {
    __shared__ __align__(16) unsigned short Wb[OC * LDA];      // 51200 B
    __shared__ __align__(16) unsigned short At[TILE_R * LDA];  // 25600 B
    const int tid = threadIdx.x;
    stage_W(Wb, W, tid);
    zero_At_pad(At, tid);

    const int lane = tid & 63;
    const int w    = tid >> 6;
    const int col  = lane & 15;
    const int q8   = (lane >> 4) * 8;
    const int r0   = (w & 1) * 32;
    const int g    = w >> 1;
    const int ct[4] = {2 * g, 2 * g + 1, 2 * g + 4, 2 * g + 5};

    float s[4] = {0.f, 0.f, 0.f, 0.f}, q[4] = {0.f, 0.f, 0.f, 0.f};

    for (int rb = blockIdx.x * TILE_R; rb < NROW; rb += gridDim.x * TILE_R) {
        __syncthreads();
        stage_tile(At, atom, nbr, idx, rb, tid);
        __syncthreads();

        f32x4 acc[2][4];
#pragma unroll
        for (int rt = 0; rt < 2; ++rt)
#pragma unroll
            for (int t = 0; t < 4; ++t) acc[rt][t] = (f32x4){0.f, 0.f, 0.f, 0.f};

#pragma unroll
        for (int kc = 0; kc < 6; ++kc) {
            const int k0 = kc * 32;
            const s16x8 a0 = *(const s16x8*)&At[(r0 + col) * LDA + k0 + q8];
            const s16x8 a1 = *(const s16x8*)&At[(r0 + 16 + col) * LDA + k0 + q8];
#pragma unroll
            for (int t = 0; t < 4; ++t) {
                const s16x8 b = *(const s16x8*)&Wb[(ct[t] * 16 + col) * LDA + k0 + q8];
                acc[0][t] = __builtin_amdgcn_mfma_f32_16x16x32_bf16(a0, b, acc[0][t], 0, 0, 0);
                acc[1][t] = __builtin_amdgcn_mfma_f32_16x16x32_bf16(a1, b, acc[1][t], 0, 0, 0);
            }
        }
#pragma unroll
        for (int t = 0; t < 4; ++t)
#pragma unroll
            for (int rt = 0; rt < 2; ++rt)
#pragma unroll
                for (int e = 0; e < 4; ++e) {
                    float v = acc[rt][t][e];
                    s[t] += v; q[t] = fmaf(v, v, q[t]);
                }
    }
#pragma unroll
    for (int t = 0; t < 4; ++t) {
        float sv = s[t], qv = q[t];
        sv += __shfl_xor(sv, 16); sv += __shfl_xor(sv, 32);
        qv += __shfl_xor(qv, 16); qv += __shfl_xor(qv, 32);
        if (lane < 16) {
            int c = ct[t] * 16 + col;
            atomicAdd(&stats[WS_SUM1 + c], sv);
            atomicAdd(&stats[WS_SUMSQ1 + c], qv);
        }
    }
}

// ---- pass 2: MFMA GEMM + BN1 + sigmoid*softplus + m-sum into d_out
__global__ __launch_bounds__(256, 2)
void k_gemm_main(const float* __restrict__ atom, const float* __restrict__ nbr,
                 const int* __restrict__ idx, const float* __restrict__ W,
                 const float* __restrict__ g1, const float* __restrict__ b1,
                 const float* __restrict__ stats, float* __restrict__ dout) {
    __shared__ __align__(16) unsigned short Wb[OC * LDA];
    __shared__ __align__(16) unsigned short At[TILE_R * LDA];
    __shared__ float S[7 * 64];
    const int tid = threadIdx.x;
    stage_W(Wb, W, tid);
    zero_At_pad(At, tid);
    for (int i = tid; i < 7 * 64; i += 256) S[i] = 0.f;

    const int lane = tid & 63;
    const int w    = tid >> 6;
    const int col  = lane & 15;
    const int q8   = (lane >> 4) * 8;
    const int r0   = (w & 1) * 32;
    const int g    = w >> 1;
    const int ct[4] = {2 * g, 2 * g + 1, 2 * g + 4, 2 * g + 5};

    const float invn = 1.f / (float)NROW;
    float sc[4], sh[4];
#pragma unroll
    for (int t = 0; t < 4; ++t) {
        int c = ct[t] * 16 + col;
        float mean = stats[WS_SUM1 + c] * invn;
        float var  = stats[WS_SUMSQ1 + c] * invn - mean * mean;
        sc[t] = g1[c] * rsqrtf(var + BN_EPS);
        sh[t] = b1[c] - mean * sc[t];
    }

    for (int rb = blockIdx.x * TILE_R; rb < NROW; rb += gridDim.x * TILE_R) {
        __syncthreads();
        stage_tile(At, atom, nbr, idx, rb, tid);
        __syncthreads();

        f32x4 acc[2][4];
#pragma unroll
        for (int rt = 0; rt < 2; ++rt)
#pragma unroll
            for (int t = 0; t < 4; ++t) acc[rt][t] = (f32x4){0.f, 0.f, 0.f, 0.f};

#pragma unroll
        for (int kc = 0; kc < 6; ++kc) {
            const int k0 = kc * 32;
            const s16x8 a0 = *(const s16x8*)&At[(r0 + col) * LDA + k0 + q8];
            const s16x8 a1 = *(const s16x8*)&At[(r0 + 16 + col) * LDA + k0 + q8];
#pragma unroll
            for (int t = 0; t < 4; ++t) {
                const s16x8 b = *(const s16x8*)&Wb[(ct[t] * 16 + col) * LDA + k0 + q8];
                acc[0][t] = __builtin_amdgcn_mfma_f32_16x16x32_bf16(a0, b, acc[0][t], 0, 0, 0);
                acc[1][t] = __builtin_amdgcn_mfma_f32_16x16x32_bf16(a1, b, acc[1][t], 0, 0, 0);
            }
        }

        const int a0i = rb / M_NBR;
#pragma unroll
        for (int p = 0; p < 2; ++p) {            // (filter t=p, core t=p+2)
            const int c = ct[p] * 16 + col;      // filter channel in [0,64)
#pragma unroll
            for (int rt = 0; rt < 2; ++rt)
#pragma unroll
                for (int e = 0; e < 4; ++e) {
                    float gF = fmaf(acc[rt][p][e],     sc[p],     sh[p]);
                    float gC = fmaf(acc[rt][p + 2][e], sc[p + 2], sh[p + 2]);
                    float v  = fsigmoid(gF) * fsoftplus(gC);
                    int row_local = r0 + rt * 16 + (lane >> 4) * 4 + e;
                    int al = (rb + row_local) / M_NBR - a0i;   // 0..6
                    atomicAdd(&S[al * 64 + c], v);
                }
        }
        __syncthreads();
        const int amax = (rb + TILE_R - 1) / M_NBR - a0i;
        for (int i = tid; i < 7 * 64; i += 256) {
            float v = S[i];
            S[i] = 0.f;
            int a = i >> 6;
            if (a <= amax) atomicAdd(&dout[(a0i + a) * 64 + (i & 63)], v);
        }
    }
}

__global__ __launch_bounds__(256, 1)
void k_bn2_stats(const float* __restrict__ dout, float* __restrict__ stats) {
    int tid = threadIdx.x;
    int c = tid & 63;
    int g = tid >> 6;
    float s = 0.f, q = 0.f;
    for (int n = blockIdx.x * 4 + g; n < N_ATOMS; n += gridDim.x * 4) {
        float v = dout[n * 64 + c];
        s += v; q = fmaf(v, v, q);
    }
    __shared__ float red[4][64];
    red[g][c] = s;
    __syncthreads();
    if (g == 0)
        atomicAdd(&stats[WS_SUM2 + c], red[0][c] + red[1][c] + red[2][c] + red[3][c]);
    __syncthreads();
    red[g][c] = q;
    __syncthreads();
    if (g == 0)
        atomicAdd(&stats[WS_SUMSQ2 + c], red[0][c] + red[1][c] + red[2][c] + red[3][c]);
}

__global__ void k_final(const float* __restrict__ atom, const float* __restrict__ g2,
                        const float* __restrict__ b2, const float* __restrict__ stats,
                        float* __restrict__ dout) {
    int i0 = blockIdx.x * blockDim.x + threadIdx.x;
    int c = i0 & 63;
    const float invn = 1.f / (float)N_ATOMS;
    float mean = stats[WS_SUM2 + c] * invn;
    float var  = stats[WS_SUMSQ2 + c] * invn - mean * mean;
    float sc   = g2[c] * rsqrtf(var + BN_EPS);
    float sh   = b2[c] - mean * sc;
    int stride = gridDim.x * blockDim.x;
    for (int i = i0; i < N_ATOMS * A_FEA; i += stride) {
        float v = fmaf(dout[i], sc, sh) + atom[i];
        dout[i] = fsoftplus(v);
    }
}

extern "C" void kernel_launch(void* const* d_in, const int* in_sizes, int n_in,
                              void* d_out, int out_size, void* d_ws, size_t ws_size,
                              hipStream_t stream) {
    const float* atom = (const float*)d_in[0];
    const float* nbr  = (const float*)d_in[1];
    const int*   idx  = (const int*)d_in[2];
    const float* W    = (const float*)d_in[3];
    // d_in[4] (bias b) is mathematically absorbed by BN1 -> unused
    const float* g1   = (const float*)d_in[5];
    const float* b1   = (const float*)d_in[6];
    const float* g2   = (const float*)d_in[7];
    const float* b2   = (const float*)d_in[8];
    float* dout  = (float*)d_out;
    float* stats = (float*)d_ws;

    k_zero<<<512, 256, 0, stream>>>(dout, stats);
    k_gemm_stats<<<512, 256, 0, stream>>>(atom, nbr, idx, W, stats);
    k_gemm_main<<<512, 256, 0, stream>>>(atom, nbr, idx, W, g1, b1, stats, dout);
    k_bn2_stats<<<256, 256, 0, stream>>>(dout, stats);
    k_final<<<512, 256, 0, stream>>>(atom, g2, b2, stats, dout);
}

// Round 4
// 493.070 us; speedup vs baseline: 4.6040x; 1.1265x over previous
//
#include <hip/hip_runtime.h>
#include <math.h>

#define N_ATOMS 50000
#define M_NBR   12
#define A_FEA   64
#define B_FEA   41
#define KF      169      // 2*A + B
#define KP      192      // padded K (6 chunks of 32)
#define LDA     200      // LDS row stride in bf16 (400 B -> free 2-way banking)
#define OC      128      // 2*A
#define NROW    600000   // N_ATOMS * M_NBR
#define TILE_R  64
#define BN_EPS  1e-5f
#define L2E     1.44269504088896340736f
#define LN2     0.693147180559945309417f

// d_ws float layout
#define WS_SUM1   0
#define WS_SUMSQ1 128
#define WS_SUM2   256
#define WS_SUMSQ2 320
#define WS_NFLOAT 384

typedef __attribute__((ext_vector_type(8))) short s16x8;
typedef __attribute__((ext_vector_type(4))) float f32x4;

__device__ __forceinline__ float fsigmoid(float x) {
    float e = __builtin_amdgcn_exp2f(-x * L2E);
    return __builtin_amdgcn_rcpf(1.f + e);
}
__device__ __forceinline__ float fsoftplus(float x) {
    float e = __builtin_amdgcn_exp2f(-fabsf(x) * L2E);
    return fmaxf(x, 0.f) + __builtin_amdgcn_logf(1.f + e) * LN2;
}
__device__ __forceinline__ unsigned short f2bf(float f) {
    unsigned int u = __float_as_uint(f);
    u += 0x7FFFu + ((u >> 16) & 1u);     // RNE
    return (unsigned short)(u >> 16);
}
__device__ __forceinline__ unsigned int pack2bf(float lo, float hi) {
    return (unsigned int)f2bf(lo) | ((unsigned int)f2bf(hi) << 16);
}

__global__ void k_zero(float* __restrict__ dout, float* __restrict__ stats) {
    int i = blockIdx.x * blockDim.x + threadIdx.x;
    int stride = gridDim.x * blockDim.x;
    for (int j = i; j < N_ATOMS * A_FEA; j += stride) dout[j] = 0.f;
    if (i < WS_NFLOAT) stats[i] = 0.f;
}

// ---- prefetch pipeline state (registers) -----------------------------------
struct Pref {
    float2 selfv[8];
    float2 gat[8];
    float  bondv[10];
    float  tailv;
    int    nbi[8];
};

__device__ __forceinline__ void issue_idx(Pref& P, const int* __restrict__ idx,
                                          int rb, int r8) {
#pragma unroll
    for (int it = 0; it < 8; ++it) P.nbi[it] = idx[rb + r8 + it * 8];
}
__device__ __forceinline__ void issue_self_bond(Pref& P, const float* __restrict__ atom,
                                                const float* __restrict__ nbr,
                                                int rb, int r8, int k2, int tid) {
#pragma unroll
    for (int it = 0; it < 8; ++it)
        P.selfv[it] = *(const float2*)(atom + ((unsigned)(rb + r8 + it * 8) / 12u) * A_FEA + k2);
#pragma unroll
    for (int it = 0; it < 10; ++it)
        P.bondv[it] = nbr[(size_t)rb * B_FEA + tid + it * 256];
    P.tailv = (tid < TILE_R * B_FEA - 2560) ? nbr[(size_t)rb * B_FEA + 2560 + tid] : 0.f;
}
__device__ __forceinline__ void issue_gat(Pref& P, const float* __restrict__ atom, int k2) {
#pragma unroll
    for (int it = 0; it < 8; ++it)
        P.gat[it] = *(const float2*)(atom + (unsigned)P.nbi[it] * A_FEA + k2);
}
__device__ __forceinline__ void write_lds(unsigned short* __restrict__ At,
                                          const Pref& P, int r8, int k2, int tid) {
#pragma unroll
    for (int it = 0; it < 8; ++it) {
        int r = r8 + it * 8;
        *(unsigned int*)&At[r * LDA + k2]         = pack2bf(P.selfv[it].x, P.selfv[it].y);
        *(unsigned int*)&At[r * LDA + A_FEA + k2] = pack2bf(P.gat[it].x, P.gat[it].y);
    }
#pragma unroll
    for (int it = 0; it < 10; ++it) {
        unsigned i = tid + it * 256;
        unsigned r = i / 41u, j = i - r * 41u;
        At[r * LDA + 2 * A_FEA + j] = f2bf(P.bondv[it]);
    }
    if (tid < TILE_R * B_FEA - 2560) {
        unsigned i = 2560 + tid;
        unsigned r = i / 41u, j = i - r * 41u;
        At[r * LDA + 2 * A_FEA + j] = f2bf(P.tailv);
    }
}
__device__ __forceinline__ void zero_At_pad(unsigned short* __restrict__ At, int tid) {
    for (unsigned i = tid; i < TILE_R * (KP - KF); i += 256) {
        unsigned r = i / (unsigned)(KP - KF);
        unsigned j = KF + (i - r * (KP - KF));
        At[r * LDA + j] = 0;
    }
}

// Per-wave W fragments (B operand) loaded once from global into registers.
__device__ __forceinline__ void load_wfrag(s16x8 bfr[4][6], const float* __restrict__ W,
                                           const int ct[4], int col, int q8) {
#pragma unroll
    for (int t = 0; t < 4; ++t) {
        const float* wr = W + (ct[t] * 16 + col) * KF;
#pragma unroll
        for (int kc = 0; kc < 6; ++kc) {
            const int kb = kc * 32 + q8;
            s16x8 f;
#pragma unroll
            for (int j = 0; j < 8; ++j) {
                int k = kb + j;
                float v = (k < KF) ? wr[k] : 0.f;
                f[j] = (short)f2bf(v);
            }
            bfr[t][kc] = f;
        }
    }
}

// ---- pass 1: MFMA GEMM, per-channel sum/sumsq (linear bias cancels in BN1)
__global__ __launch_bounds__(256, 2)
void k_gemm_stats(const float* __restrict__ atom, const float* __restrict__ nbr,
                  const int* __restrict__ idx, const float* __restrict__ W,
                  float* __restrict__ stats) {
    __shared__ __align__(16) unsigned short At[TILE_R * LDA];  // 25600 B
    const int tid = threadIdx.x;
    const int r8 = tid >> 5;
    const int k2 = (tid & 31) * 2;
    zero_At_pad(At, tid);

    const int lane = tid & 63;
    const int w    = tid >> 6;
    const int col  = lane & 15;
    const int q8   = (lane >> 4) * 8;
    const int r0   = (w & 1) * 32;
    const int g    = w >> 1;
    const int ct[4] = {2 * g, 2 * g + 1, 2 * g + 4, 2 * g + 5};

    s16x8 bfr[4][6];
    load_wfrag(bfr, W, ct, col, q8);

    float s[4] = {0.f, 0.f, 0.f, 0.f}, q[4] = {0.f, 0.f, 0.f, 0.f};

    const int step = gridDim.x * TILE_R;
    const int rb0 = blockIdx.x * TILE_R;
    Pref P;
    issue_idx(P, idx, rb0, r8);
    issue_self_bond(P, atom, nbr, rb0, r8, k2, tid);
    issue_gat(P, atom, k2);
    {
        int rb1 = rb0 + step;
        issue_idx(P, idx, (rb1 < NROW) ? rb1 : rb0, r8);
    }

    for (int rb = rb0; rb < NROW; rb += step) {
        __syncthreads();                 // prior tile's LDS reads complete
        write_lds(At, P, r8, k2, tid);   // waits on tile-rb loads (in flight ~1 tile)
        __syncthreads();

        int rbn = rb + step;
        int rbsn = (rbn < NROW) ? rbn : rb;
        issue_self_bond(P, atom, nbr, rbsn, r8, k2, tid);
        issue_gat(P, atom, k2);          // nbi = idx(rbn), issued last iter
        int rbnn = rbn + step;
        issue_idx(P, idx, (rbnn < NROW) ? rbnn : rbsn, r8);

        f32x4 acc[2][4];
#pragma unroll
        for (int rt = 0; rt < 2; ++rt)
#pragma unroll
            for (int t = 0; t < 4; ++t) acc[rt][t] = (f32x4){0.f, 0.f, 0.f, 0.f};

#pragma unroll
        for (int kc = 0; kc < 6; ++kc) {
            const int k0 = kc * 32;
            const s16x8 a0 = *(const s16x8*)&At[(r0 + col) * LDA + k0 + q8];
            const s16x8 a1 = *(const s16x8*)&At[(r0 + 16 + col) * LDA + k0 + q8];
#pragma unroll
            for (int t = 0; t < 4; ++t) {
                acc[0][t] = __builtin_amdgcn_mfma_f32_16x16x32_bf16(a0, bfr[t][kc], acc[0][t], 0, 0, 0);
                acc[1][t] = __builtin_amdgcn_mfma_f32_16x16x32_bf16(a1, bfr[t][kc], acc[1][t], 0, 0, 0);
            }
        }
#pragma unroll
        for (int t = 0; t < 4; ++t)
#pragma unroll
            for (int rt = 0; rt < 2; ++rt)
#pragma unroll
                for (int e = 0; e < 4; ++e) {
                    float v = acc[rt][t][e];
                    s[t] += v; q[t] = fmaf(v, v, q[t]);
                }
    }
#pragma unroll
    for (int t = 0; t < 4; ++t) {
        float sv = s[t], qv = q[t];
        sv += __shfl_xor(sv, 16); sv += __shfl_xor(sv, 32);
        qv += __shfl_xor(qv, 16); qv += __shfl_xor(qv, 32);
        if (lane < 16) {
            int c = ct[t] * 16 + col;
            atomicAdd(&stats[WS_SUM1 + c], sv);
            atomicAdd(&stats[WS_SUMSQ1 + c], qv);
        }
    }
}

// ---- pass 2: MFMA GEMM + BN1 + sigmoid*softplus + m-sum into d_out
__global__ __launch_bounds__(256, 2)
void k_gemm_main(const float* __restrict__ atom, const float* __restrict__ nbr,
                 const int* __restrict__ idx, const float* __restrict__ W,
                 const float* __restrict__ g1, const float* __restrict__ b1,
                 const float* __restrict__ stats, float* __restrict__ dout) {
    __shared__ __align__(16) unsigned short At[TILE_R * LDA];
    __shared__ float S[7 * 64];
    const int tid = threadIdx.x;
    const int r8 = tid >> 5;
    const int k2 = (tid & 31) * 2;
    zero_At_pad(At, tid);
    for (int i = tid; i < 7 * 64; i += 256) S[i] = 0.f;

    const int lane = tid & 63;
    const int w    = tid >> 6;
    const int col  = lane & 15;
    const int q8   = (lane >> 4) * 8;
    const int r0   = (w & 1) * 32;
    const int g    = w >> 1;
    const int ct[4] = {2 * g, 2 * g + 1, 2 * g + 4, 2 * g + 5};

    s16x8 bfr[4][6];
    load_wfrag(bfr, W, ct, col, q8);

    const float invn = 1.f / (float)NROW;
    float sc[4], sh[4];
#pragma unroll
    for (int t = 0; t < 4; ++t) {
        int c = ct[t] * 16 + col;
        float mean = stats[WS_SUM1 + c] * invn;
        float var  = stats[WS_SUMSQ1 + c] * invn - mean * mean;
        sc[t] = g1[c] * rsqrtf(var + BN_EPS);
        sh[t] = b1[c] - mean * sc[t];
    }

    const int step = gridDim.x * TILE_R;
    const int rb0 = blockIdx.x * TILE_R;
    Pref P;
    issue_idx(P, idx, rb0, r8);
    issue_self_bond(P, atom, nbr, rb0, r8, k2, tid);
    issue_gat(P, atom, k2);
    {
        int rb1 = rb0 + step;
        issue_idx(P, idx, (rb1 < NROW) ? rb1 : rb0, r8);
    }

    for (int rb = rb0; rb < NROW; rb += step) {
        __syncthreads();
        write_lds(At, P, r8, k2, tid);
        __syncthreads();

        int rbn = rb + step;
        int rbsn = (rbn < NROW) ? rbn : rb;
        issue_self_bond(P, atom, nbr, rbsn, r8, k2, tid);
        issue_gat(P, atom, k2);
        int rbnn = rbn + step;
        issue_idx(P, idx, (rbnn < NROW) ? rbnn : rbsn, r8);

        f32x4 acc[2][4];
#pragma unroll
        for (int rt = 0; rt < 2; ++rt)
#pragma unroll
            for (int t = 0; t < 4; ++t) acc[rt][t] = (f32x4){0.f, 0.f, 0.f, 0.f};

#pragma unroll
        for (int kc = 0; kc < 6; ++kc) {
            const int k0 = kc * 32;
            const s16x8 a0 = *(const s16x8*)&At[(r0 + col) * LDA + k0 + q8];
            const s16x8 a1 = *(const s16x8*)&At[(r0 + 16 + col) * LDA + k0 + q8];
#pragma unroll
            for (int t = 0; t < 4; ++t) {
                acc[0][t] = __builtin_amdgcn_mfma_f32_16x16x32_bf16(a0, bfr[t][kc], acc[0][t], 0, 0, 0);
                acc[1][t] = __builtin_amdgcn_mfma_f32_16x16x32_bf16(a1, bfr[t][kc], acc[1][t], 0, 0, 0);
            }
        }

        const int a0i = rb / M_NBR;
#pragma unroll
        for (int p = 0; p < 2; ++p) {            // (filter t=p, core t=p+2)
            const int c = ct[p] * 16 + col;      // filter channel in [0,64)
#pragma unroll
            for (int rt = 0; rt < 2; ++rt)
#pragma unroll
                for (int e = 0; e < 4; ++e) {
                    float gF = fmaf(acc[rt][p][e],     sc[p],     sh[p]);
                    float gC = fmaf(acc[rt][p + 2][e], sc[p + 2], sh[p + 2]);
                    float v  = fsigmoid(gF) * fsoftplus(gC);
                    int row_local = r0 + rt * 16 + (lane >> 4) * 4 + e;
                    int al = (rb + row_local) / M_NBR - a0i;   // 0..6
                    atomicAdd(&S[al * 64 + c], v);
                }
        }
        __syncthreads();
        const int amax = (rb + TILE_R - 1) / M_NBR - a0i;
        for (int i = tid; i < 7 * 64; i += 256) {
            float v = S[i];
            S[i] = 0.f;
            int a = i >> 6;
            if (a <= amax) atomicAdd(&dout[(a0i + a) * 64 + (i & 63)], v);
        }
    }
}

__global__ __launch_bounds__(256, 1)
void k_bn2_stats(const float* __restrict__ dout, float* __restrict__ stats) {
    int tid = threadIdx.x;
    int c = tid & 63;
    int g = tid >> 6;
    float s = 0.f, q = 0.f;
    for (int n = blockIdx.x * 4 + g; n < N_ATOMS; n += gridDim.x * 4) {
        float v = dout[n * 64 + c];
        s += v; q = fmaf(v, v, q);
    }
    __shared__ float red[4][64];
    red[g][c] = s;
    __syncthreads();
    if (g == 0)
        atomicAdd(&stats[WS_SUM2 + c], red[0][c] + red[1][c] + red[2][c] + red[3][c]);
    __syncthreads();
    red[g][c] = q;
    __syncthreads();
    if (g == 0)
        atomicAdd(&stats[WS_SUMSQ2 + c], red[0][c] + red[1][c] + red[2][c] + red[3][c]);
}

__global__ void k_final(const float* __restrict__ atom, const float* __restrict__ g2,
                        const float* __restrict__ b2, const float* __restrict__ stats,
                        float* __restrict__ dout) {
    int i0 = blockIdx.x * blockDim.x + threadIdx.x;
    int c = i0 & 63;
    const float invn = 1.f / (float)N_ATOMS;
    float mean = stats[WS_SUM2 + c] * invn;
    float var  = stats[WS_SUMSQ2 + c] * invn - mean * mean;
    float sc   = g2[c] * rsqrtf(var + BN_EPS);
    float sh   = b2[c] - mean * sc;
    int stride = gridDim.x * blockDim.x;
    for (int i = i0; i < N_ATOMS * A_FEA; i += stride) {
        float v = fmaf(dout[i], sc, sh) + atom[i];
        dout[i] = fsoftplus(v);
    }
}

extern "C" void kernel_launch(void* const* d_in, const int* in_sizes, int n_in,
                              void* d_out, int out_size, void* d_ws, size_t ws_size,
                              hipStream_t stream) {
    const float* atom = (const float*)d_in[0];
    const float* nbr  = (const float*)d_in[1];
    const int*   idx  = (const int*)d_in[2];
    const float* W    = (const float*)d_in[3];
    // d_in[4] (bias b) is mathematically absorbed by BN1 -> unused
    const float* g1   = (const float*)d_in[5];
    const float* b1   = (const float*)d_in[6];
    const float* g2   = (const float*)d_in[7];
    const float* b2   = (const float*)d_in[8];
    float* dout  = (float*)d_out;
    float* stats = (float*)d_ws;

    k_zero<<<512, 256, 0, stream>>>(dout, stats);
    k_gemm_stats<<<512, 256, 0, stream>>>(atom, nbr, idx, W, stats);
    k_gemm_main<<<512, 256, 0, stream>>>(atom, nbr, idx, W, g1, b1, stats, dout);
    k_bn2_stats<<<256, 256, 0, stream>>>(dout, stats);
    k_final<<<512, 256, 0, stream>>>(atom, g2, b2, stats, dout);
}